// Round 1
// 371.445 us; speedup vs baseline: 1.0990x; 1.0990x over previous
//
#include <hip/hip_runtime.h>
#include <stdint.h>

#define BATCH 16384
#define IN_F 2048
#define OUT_F 2048

typedef unsigned short u16;
typedef __attribute__((ext_vector_type(8))) short bf16x8;
typedef __attribute__((ext_vector_type(4))) float f32x4;

__device__ __forceinline__ u16 f2bf(float f) {
  union { float f; uint32_t u; } v; v.f = f;
  uint32_t u = v.u;
  u += 0x7FFFu + ((u >> 16) & 1u);   // round-to-nearest-even
  return (u16)(u >> 16);
}

// ---- prologue: fused fp32 -> bf16 conversion (x and w*mask in one launch) ----

__global__ void cvt_fused(const float4* __restrict__ x, const float4* __restrict__ w,
                          const float4* __restrict__ m, u16* __restrict__ xb,
                          u16* __restrict__ wb) {
  const int NX = BATCH * IN_F / 4;
  int i = blockIdx.x * 256 + threadIdx.x;
  if (i < NX) {
    float4 v = x[i];
    uint2 p;
    p.x = (uint32_t)f2bf(v.x) | ((uint32_t)f2bf(v.y) << 16);
    p.y = (uint32_t)f2bf(v.z) | ((uint32_t)f2bf(v.w) << 16);
    ((uint2*)xb)[i] = p;
  } else {
    int j = i - NX;
    float4 wv = w[j];
    float4 mv = m[j];
    uint2 p;
    p.x = (uint32_t)f2bf(wv.x * mv.x) | ((uint32_t)f2bf(wv.y * mv.y) << 16);
    p.y = (uint32_t)f2bf(wv.z * mv.z) | ((uint32_t)f2bf(wv.w * mv.w) << 16);
    ((uint2*)wb)[j] = p;
  }
}

// ---- async global->LDS 16B copy ----

__device__ __forceinline__ void async_cp16(const void* g, void* l) {
  __builtin_amdgcn_global_load_lds(
      (const __attribute__((address_space(1))) void*)g,
      (__attribute__((address_space(3))) void*)l,
      16, 0, 0);
}

// ---- bf16 MFMA GEMM: C[M][N] = A[M][K] * B[N][K]^T + bias ----
// 256x256 tile, BK=32, 512 threads = 8 waves (2M x 4N), each wave 128x64 out
// (8x4 16x16 frags, acc = 128 VGPR). LDS: 4-slot ring of 32 KB K-tiles
// (A 16K + B 16K each, 128 KiB total), depth-3 prefetch via global_load_lds.
// Counted s_waitcnt vmcnt(8) ONCE per K-iter (never 0 in the loop): the wait
// retires stages issued 2 iters ago, so tile t+1 is resident when iter t+1
// starts; slot (t+3)&3 being overwritten was last read at iter t-1 (done
// before iter t's first barrier), so no write-after-read race.
// Chunk swizzle (verified, bank-conflict==0): LDS row = 32 bf16 (64 B) in
// 4x16B chunks; physical chunk c holds logical chunk c ^ ((row>>1)&3); the
// staging pre-swizzles the GLOBAL source column (global_load_lds dest must
// stay linear), the ds_read applies the same XOR.

#define BK 32
#define NT (IN_F / BK)   // 64 K-tiles

__global__ __launch_bounds__(512, 2) void gemm_bf16(const u16* __restrict__ A,
                                                    const u16* __restrict__ B,
                                                    const float* __restrict__ bias,
                                                    float* __restrict__ C) {
  __shared__ __align__(128) char smem[4 * 32768];
  const int K = IN_F, N = OUT_F;
  const int tid = threadIdx.x;
  const int lane = tid & 63, wave = tid >> 6;
  const int wm = wave >> 2;          // 0..1  (M half)
  const int wn = wave & 3;           // 0..3  (N quarter)
  const long bn = (long)blockIdx.x * 256;   // N-blocks in x: id%8 = bn-stripe -> per-XCD B L2 residency
  const long bm = (long)blockIdx.y * 256;

  // ---- staging addresses: thread tid stages row sr=tid>>2, phys chunk sc=tid&3
  const int sr = tid >> 2, sc = tid & 3;
  const int scs = sc ^ ((sr >> 1) & 3);          // logical (global) chunk for this slot
  const u16* gA = A + (bm + sr) * K + scs * 8;
  const u16* gB = B + (bn + sr) * K + scs * 8;
  const long hiK = 128L * K;                     // +128 rows; (r+128)>>1 == r>>1 (mod 4)
  const int ldst = tid * 16;                     // linear dest within an 8 KB region

  auto stageA = [&](int slot, int kt) {
    char* sb = smem + slot * 32768;
    const long ko = (long)kt * BK;
    async_cp16(gA + ko, sb + ldst);              // rows 0..127
    async_cp16(gA + hiK + ko, sb + 8192 + ldst); // rows 128..255
  };
  auto stageB = [&](int slot, int kt) {
    char* sb = smem + slot * 32768 + 16384;
    const long ko = (long)kt * BK;
    async_cp16(gB + ko, sb + ldst);
    async_cp16(gB + hiK + ko, sb + 8192 + ldst);
  };

  // ---- fragment read offset (same for every frag: row-swizzle depends only on lane&15)
  const int rl = lane & 15;
  const int q = lane >> 4;
  const int fb = rl * 64 + ((q ^ ((rl >> 1) & 3)) * 16);

  f32x4 acc[8][4];
#pragma unroll
  for (int i = 0; i < 8; i++)
#pragma unroll
    for (int j = 0; j < 4; j++)
#pragma unroll
      for (int r = 0; r < 4; r++) acc[i][j][r] = 0.0f;

  // ---- prologue: stage tiles 0,1,2 (12 issues); retire tile 0 (vmcnt 8)
  stageA(0, 0); stageB(0, 0);
  stageA(1, 1); stageB(1, 1);
  stageA(2, 2); stageB(2, 2);
  asm volatile("s_waitcnt vmcnt(8)" ::: "memory");
  __builtin_amdgcn_s_barrier();
  __builtin_amdgcn_sched_barrier(0);

  for (int t = 0; t < NT; ++t) {
    const int slot = t & 3;
    const int kt3 = (t + 3 < NT) ? t + 3 : NT - 1;   // clamped tail: harmless re-stage into dead slots
    const int s3 = (t + 3) & 3;
    const char* sA = smem + slot * 32768 + wm * 8192;
    const char* sB = smem + slot * 32768 + 16384 + wn * 4096;

    // ---- phase 1: read A(mh0) + B, issue A-stage for tile t+3
    bf16x8 af0[4], af1[4], bf[4];
#pragma unroll
    for (int i = 0; i < 4; i++) af0[i] = *(const bf16x8*)(sA + i * 1024 + fb);
#pragma unroll
    for (int j = 0; j < 4; j++) bf[j] = *(const bf16x8*)(sB + j * 1024 + fb);
    stageA(s3, kt3);
    __builtin_amdgcn_s_barrier();
    __builtin_amdgcn_s_setprio(1);
#pragma unroll
    for (int i = 0; i < 4; i++)
#pragma unroll
      for (int j = 0; j < 4; j++)
        acc[i][j] = __builtin_amdgcn_mfma_f32_16x16x32_bf16(af0[i], bf[j], acc[i][j], 0, 0, 0);
    __builtin_amdgcn_s_setprio(0);
    __builtin_amdgcn_s_barrier();

    // ---- phase 2: read A(mh1), issue B-stage for tile t+3
#pragma unroll
    for (int i = 0; i < 4; i++) af1[i] = *(const bf16x8*)(sA + 4096 + i * 1024 + fb);
    stageB(s3, kt3);
    __builtin_amdgcn_s_barrier();
    __builtin_amdgcn_s_setprio(1);
#pragma unroll
    for (int i = 0; i < 4; i++)
#pragma unroll
      for (int j = 0; j < 4; j++)
        acc[4 + i][j] = __builtin_amdgcn_mfma_f32_16x16x32_bf16(af1[i], bf[j], acc[4 + i][j], 0, 0, 0);
    __builtin_amdgcn_s_setprio(0);
    // counted retire: completes stages issued at iter t-2 => tile t+1 resident
    asm volatile("s_waitcnt vmcnt(8)" ::: "memory");
    __builtin_amdgcn_s_barrier();
    __builtin_amdgcn_sched_barrier(0);
  }

  // drain leftover (clamped tail) stages before LDS goes away
  asm volatile("s_waitcnt vmcnt(0)" ::: "memory");

  // ---- epilogue: C/D layout col=lane&15, row=(lane>>4)*4+r  [m89-verified]
  const int cn = lane & 15;
  const int crow = (lane >> 4) * 4;
#pragma unroll
  for (int j = 0; j < 4; j++) {
    const long n = bn + wn * 64 + j * 16 + cn;
    const float bv = bias[n];
#pragma unroll
    for (int i = 0; i < 8; i++) {
      const long m0 = bm + wm * 128 + i * 16 + crow;
      float* cp = C + m0 * N + n;
#pragma unroll
      for (int r = 0; r < 4; r++)
        cp[(long)r * N] = acc[i][j][r] + bv;
    }
  }
}

// ---- fallback (only if d_ws is too small): exact fp32, slow but correct ----

__global__ void naive_kernel(const float* __restrict__ x, const float* __restrict__ w,
                             const float* __restrict__ bias, const float* __restrict__ m,
                             float* __restrict__ out) {
  size_t idx = (size_t)blockIdx.x * 256 + threadIdx.x;
  int o = (int)(idx % OUT_F);
  size_t b = idx / OUT_F;
  float s = bias[o];
  const float* xr = x + b * IN_F;
  const float* wr = w + (size_t)o * IN_F;
  const float* mr = m + (size_t)o * IN_F;
  for (int k = 0; k < IN_F; k++) s += xr[k] * wr[k] * mr[k];
  out[idx] = s;
}

extern "C" void kernel_launch(void* const* d_in, const int* in_sizes, int n_in,
                              void* d_out, int out_size, void* d_ws, size_t ws_size,
                              hipStream_t stream) {
  const float* x = (const float*)d_in[0];
  const float* w = (const float*)d_in[1];
  const float* bias = (const float*)d_in[2];
  const float* mask = (const float*)d_in[3];
  float* out = (float*)d_out;

  const size_t xb_elems = (size_t)BATCH * IN_F;       // 33.5M bf16 = 64 MB
  const size_t wm_elems = (size_t)OUT_F * IN_F;       // 4.2M bf16 = 8 MB
  const size_t need = (xb_elems + wm_elems) * sizeof(u16);

  if (ws_size >= need) {
    u16* xb = (u16*)d_ws;
    u16* wm = xb + xb_elems;
    const uint32_t nblk = (uint32_t)((xb_elems + wm_elems) / 4 / 256);
    cvt_fused<<<nblk, 256, 0, stream>>>((const float4*)x, (const float4*)w,
                                        (const float4*)mask, xb, wm);
    gemm_bf16<<<dim3(OUT_F / 256, BATCH / 256), 512, 0, stream>>>(xb, wm, bias, out);
  } else {
    naive_kernel<<<(uint32_t)(((size_t)BATCH * OUT_F) / 256), 256, 0, stream>>>(x, w, bias, mask, out);
  }
}

// Round 2
// 360.595 us; speedup vs baseline: 1.1321x; 1.0301x over previous
//
#include <hip/hip_runtime.h>
#include <stdint.h>

#define BATCH 16384
#define IN_F 2048
#define OUT_F 2048

typedef unsigned short u16;
typedef __attribute__((ext_vector_type(8))) short bf16x8;
typedef __attribute__((ext_vector_type(4))) float f32x4;

__device__ __forceinline__ u16 f2bf(float f) {
  union { float f; uint32_t u; } v; v.f = f;
  uint32_t u = v.u;
  u += 0x7FFFu + ((u >> 16) & 1u);   // round-to-nearest-even
  return (u16)(u >> 16);
}

// ---- prologue: fused fp32 -> bf16 conversion (x and w*mask in one launch) ----

__global__ void cvt_fused(const float4* __restrict__ x, const float4* __restrict__ w,
                          const float4* __restrict__ m, u16* __restrict__ xb,
                          u16* __restrict__ wb) {
  const int NX = BATCH * IN_F / 4;
  int i = blockIdx.x * 256 + threadIdx.x;
  if (i < NX) {
    float4 v = x[i];
    uint2 p;
    p.x = (uint32_t)f2bf(v.x) | ((uint32_t)f2bf(v.y) << 16);
    p.y = (uint32_t)f2bf(v.z) | ((uint32_t)f2bf(v.w) << 16);
    ((uint2*)xb)[i] = p;
  } else {
    int j = i - NX;
    float4 wv = w[j];
    float4 mv = m[j];
    uint2 p;
    p.x = (uint32_t)f2bf(wv.x * mv.x) | ((uint32_t)f2bf(wv.y * mv.y) << 16);
    p.y = (uint32_t)f2bf(wv.z * mv.z) | ((uint32_t)f2bf(wv.w * mv.w) << 16);
    ((uint2*)wb)[j] = p;
  }
}

// ---- async global->LDS 16B copy ----

__device__ __forceinline__ void async_cp16(const void* g, void* l) {
  __builtin_amdgcn_global_load_lds(
      (const __attribute__((address_space(1))) void*)g,
      (__attribute__((address_space(3))) void*)l,
      16, 0, 0);
}

// ---- bf16 MFMA GEMM: C[M][N] = A[M][K] * B[N][K]^T + bias ----
// 256x256 tile, BK=32, 512 threads = 8 waves (2M x 4N), each wave 128x64 out.
// 4-slot LDS ring (128 KiB), depth-3 prefetch, counted vmcnt(4) ONCE per iter.
// Register-prefetch pipeline (this round's change): fragments for tile t+1
// are ds_read DURING iter t's MFMA clusters (af1 under cluster 1, next
// af0/bf under cluster 2), so LDS reads hide under the matrix pipe instead
// of alternating with it. One s_barrier per iter (slot-overwrite protection).
// Invariant at end of iter t (after vmcnt(4)): resident tiles <= t+2,
// in-flight = tile t+3 only. So prefetch reads of slot (t+1)&3 during
// iter t are safe (tile t+1 retired by every wave's vmcnt at end of t-1,
// barrier since). Stage at iter-t top overwrites slot (t+3)&3 = (t-1)&3,
// whose last reads (af1 of tile t-1) completed before iter t-1's closing
// barrier (lgkm drained before their MFMA use).
// Chunk swizzle unchanged (measured 0 bank conflicts): physical chunk c of
// row r holds logical chunk c ^ ((r>>1)&3); staging pre-swizzles the global
// source column, ds_read applies the same XOR.

#define BK 32
#define NT (IN_F / BK)   // 64 K-tiles

__global__ __launch_bounds__(512, 2) void gemm_bf16(const u16* __restrict__ A,
                                                    const u16* __restrict__ B,
                                                    const float* __restrict__ bias,
                                                    float* __restrict__ C) {
  __shared__ __align__(128) char smem[4 * 32768];
  const int K = IN_F, N = OUT_F;
  const int tid = threadIdx.x;
  const int lane = tid & 63, wave = tid >> 6;
  const int wm = wave >> 2;          // 0..1  (M half)
  const int wn = wave & 3;           // 0..3  (N quarter)
  const long bn = (long)blockIdx.x * 256;   // x = bn-stripe: each XCD keeps its B panel L2-resident
  const long bm = (long)blockIdx.y * 256;

  // ---- staging: thread tid stages row sr=tid>>2, phys chunk sc=tid&3
  const int sr = tid >> 2, sc = tid & 3;
  const int scs = sc ^ ((sr >> 1) & 3);
  const u16* gA = A + (bm + sr) * K + scs * 8;
  const u16* gB = B + (bn + sr) * K + scs * 8;
  const long hiK = 128L * K;                 // (r+128)>>1 == r>>1 (mod 4): same swizzle
  const int ldst = tid * 16;

  auto stageA = [&](int slot, int kt) {
    char* sb = smem + slot * 32768;
    const long ko = (long)kt * BK;
    async_cp16(gA + ko, sb + ldst);
    async_cp16(gA + hiK + ko, sb + 8192 + ldst);
  };
  auto stageB = [&](int slot, int kt) {
    char* sb = smem + slot * 32768 + 16384;
    const long ko = (long)kt * BK;
    async_cp16(gB + ko, sb + ldst);
    async_cp16(gB + hiK + ko, sb + 8192 + ldst);
  };

  // ---- fragment read offset (row-swizzle depends only on lane&15)
  const int rl = lane & 15;
  const int q = lane >> 4;
  const int fb = rl * 64 + ((q ^ ((rl >> 1) & 3)) * 16);
  const int aoff = wm * 8192;
  const int boff = 16384 + wn * 4096;

  f32x4 acc[8][4];
#pragma unroll
  for (int i = 0; i < 8; i++)
#pragma unroll
    for (int j = 0; j < 4; j++)
#pragma unroll
      for (int r = 0; r < 4; r++) acc[i][j][r] = 0.0f;

  // ---- prologue: stage tiles 0,1,2; retire tiles 0 and 1 (vmcnt 4)
  stageA(0, 0); stageB(0, 0);
  stageA(1, 1); stageB(1, 1);
  stageA(2, 2); stageB(2, 2);
  asm volatile("s_waitcnt vmcnt(4)" ::: "memory");
  __builtin_amdgcn_s_barrier();

  // preload current-iter fragments (tile 0) into the A-set
  bf16x8 afA[4], bfA[4], afB[4], bfB[4];
#pragma unroll
  for (int i = 0; i < 4; i++) afA[i] = *(const bf16x8*)(smem + aoff + i * 1024 + fb);
#pragma unroll
  for (int j = 0; j < 4; j++) bfA[j] = *(const bf16x8*)(smem + boff + j * 1024 + fb);

  // BODY: stage t+3; read af1 under cluster 1; read next-iter af0/bf (tile
  // t+1, slot (t+1)&3) under cluster 2; counted vmcnt; one barrier.
#define BODY(T, curA, curB, nxtA, nxtB)                                          \
  do {                                                                           \
    const int t_ = (T);                                                          \
    const int slot_ = t_ & 3, s1_ = (t_ + 1) & 3, s3_ = (t_ + 3) & 3;            \
    const int kt3_ = (t_ + 3 < NT) ? t_ + 3 : NT - 1;                            \
    const char* sA_ = smem + slot_ * 32768 + aoff;                               \
    const char* sA1_ = smem + s1_ * 32768 + aoff;                                \
    const char* sB1_ = smem + s1_ * 32768 + boff;                                \
    stageA(s3_, kt3_);                                                           \
    stageB(s3_, kt3_);                                                           \
    bf16x8 af1_[4];                                                              \
    _Pragma("unroll")                                                            \
    for (int i = 0; i < 4; i++) af1_[i] = *(const bf16x8*)(sA_ + 4096 + i * 1024 + fb); \
    __builtin_amdgcn_s_setprio(1);                                               \
    _Pragma("unroll")                                                            \
    for (int i = 0; i < 4; i++)                                                  \
      _Pragma("unroll")                                                          \
      for (int j = 0; j < 4; j++)                                                \
        acc[i][j] = __builtin_amdgcn_mfma_f32_16x16x32_bf16(curA[i], curB[j], acc[i][j], 0, 0, 0); \
    __builtin_amdgcn_s_setprio(0);                                               \
    _Pragma("unroll")                                                            \
    for (int i = 0; i < 4; i++) nxtA[i] = *(const bf16x8*)(sA1_ + i * 1024 + fb); \
    _Pragma("unroll")                                                            \
    for (int j = 0; j < 4; j++) nxtB[j] = *(const bf16x8*)(sB1_ + j * 1024 + fb); \
    __builtin_amdgcn_s_setprio(1);                                               \
    _Pragma("unroll")                                                            \
    for (int i = 0; i < 4; i++)                                                  \
      _Pragma("unroll")                                                          \
      for (int j = 0; j < 4; j++)                                                \
        acc[4 + i][j] = __builtin_amdgcn_mfma_f32_16x16x32_bf16(af1_[i], curB[j], acc[4 + i][j], 0, 0, 0); \
    __builtin_amdgcn_s_setprio(0);                                               \
    asm volatile("s_waitcnt vmcnt(4)" ::: "memory");                             \
    __builtin_amdgcn_s_barrier();                                                \
  } while (0)

  for (int t = 0; t < NT; t += 2) {
    BODY(t, afA, bfA, afB, bfB);
    BODY(t + 1, afB, bfB, afA, bfA);
  }
#undef BODY

  // drain leftover clamped-tail stages before LDS goes away
  asm volatile("s_waitcnt vmcnt(0)" ::: "memory");

  // ---- epilogue: C/D layout col=lane&15, row=(lane>>4)*4+r  [m89-verified]
  const int cn = lane & 15;
  const int crow = (lane >> 4) * 4;
#pragma unroll
  for (int j = 0; j < 4; j++) {
    const long n = bn + wn * 64 + j * 16 + cn;
    const float bv = bias[n];
#pragma unroll
    for (int i = 0; i < 8; i++) {
      const long m0 = bm + wm * 128 + i * 16 + crow;
      float* cp = C + m0 * N + n;
#pragma unroll
      for (int r = 0; r < 4; r++)
        cp[(long)r * N] = acc[i][j][r] + bv;
    }
  }
}

// ---- fallback (only if d_ws is too small): exact fp32, slow but correct ----

__global__ void naive_kernel(const float* __restrict__ x, const float* __restrict__ w,
                             const float* __restrict__ bias, const float* __restrict__ m,
                             float* __restrict__ out) {
  size_t idx = (size_t)blockIdx.x * 256 + threadIdx.x;
  int o = (int)(idx % OUT_F);
  size_t b = idx / OUT_F;
  float s = bias[o];
  const float* xr = x + b * IN_F;
  const float* wr = w + (size_t)o * IN_F;
  const float* mr = m + (size_t)o * IN_F;
  for (int k = 0; k < IN_F; k++) s += xr[k] * wr[k] * mr[k];
  out[idx] = s;
}

extern "C" void kernel_launch(void* const* d_in, const int* in_sizes, int n_in,
                              void* d_out, int out_size, void* d_ws, size_t ws_size,
                              hipStream_t stream) {
  const float* x = (const float*)d_in[0];
  const float* w = (const float*)d_in[1];
  const float* bias = (const float*)d_in[2];
  const float* mask = (const float*)d_in[3];
  float* out = (float*)d_out;

  const size_t xb_elems = (size_t)BATCH * IN_F;       // 33.5M bf16 = 64 MB
  const size_t wm_elems = (size_t)OUT_F * IN_F;       // 4.2M bf16 = 8 MB
  const size_t need = (xb_elems + wm_elems) * sizeof(u16);

  if (ws_size >= need) {
    u16* xb = (u16*)d_ws;
    u16* wm = xb + xb_elems;
    const uint32_t nblk = (uint32_t)((xb_elems + wm_elems) / 4 / 256);
    cvt_fused<<<nblk, 256, 0, stream>>>((const float4*)x, (const float4*)w,
                                        (const float4*)mask, xb, wm);
    gemm_bf16<<<dim3(OUT_F / 256, BATCH / 256), 512, 0, stream>>>(xb, wm, bias, out);
  } else {
    naive_kernel<<<(uint32_t)(((size_t)BATCH * OUT_F) / 256), 256, 0, stream>>>(x, w, bias, mask, out);
  }
}